// Round 10
// baseline (23.749 us; speedup 1.0000x reference)
//
#include <hip/hip_runtime.h>
#include <math.h>

typedef float v2f __attribute__((ext_vector_type(2)));

// Packed d^2 accumulate for a QUERY PAIR against one ref point.
// Ref arrives as its natural float4 subreg pairs xy=(x,y), zw=(z,w=|r|^2);
// op_sel/op_sel_hi broadcast the needed scalar half to both lanes, so no
// duplicated-coefficient registers are needed anywhere.
//   t = x*axp + w ; t = y*ayp + t ; t = z*azp + t     (per-lane fp32 FMA)
static __device__ __forceinline__ v2f pk3(v2f xy, v2f zw, v2f axp, v2f ayp, v2f azp) {
    v2f t;
    asm("v_pk_fma_f32 %0, %1, %2, %3 op_sel:[0,0,1] op_sel_hi:[0,1,1]"  // x*axp + w
        : "=v"(t) : "v"(xy), "v"(axp), "v"(zw));
    asm("v_pk_fma_f32 %0, %1, %2, %0 op_sel:[1,0,0] op_sel_hi:[1,1,1]"  // y*ayp + t
        : "+v"(t) : "v"(xy), "v"(ayp));
    asm("v_pk_fma_f32 %0, %1, %2, %0 op_sel:[0,0,0] op_sel_hi:[0,1,1]"  // z*azp + t
        : "+v"(t) : "v"(zw), "v"(azp));
    return t;
}

#define NBATCH 8
#define PTOT   4096
#define NG     2048              // points per group
#define S      32                // ref slices per problem  (R10: 16 -> 32)
#define SLEN   (NG / S)          // 64 refs per slice
#define QPT    8                 // queries per thread (4 packed pairs)
#define NT     256               // threads per block
#define NPROB  32                // 8 batches x 2 groups x 2 directions
#define NBLK1  (NPROB * S)       // 1024 blocks -> 4 blocks/CU -> 4 waves/SIMD
#define NPART  (NPROB * S * NG)  // 2M floats (8 MB)

// Pass 1: identical to the R9 kernel except S (occupancy experiment).
// One block = (problem, slice of 64 refs); 4 blocks/CU for latency hiding.
__global__ __launch_bounds__(256) void chamfer_pass1(
    const float* __restrict__ x, const float* __restrict__ y,
    float* __restrict__ pmin)
{
    __shared__ float  raw[SLEN * 3];   // 768 B
    __shared__ float4 ref[SLEN];       // 1 KiB (x,y,z,|r|^2)

    const int blk   = blockIdx.x;
    const int tid   = threadIdx.x;
    const int slice = blk & (S - 1);
    const int prob  = blk >> 5;              // 0..31
    const int dir   = prob >> 4;             // 0: x->y, 1: y->x
    const int bg    = prob & 15;
    const int b     = bg >> 1;               // batch
    const int g     = bg & 1;                // group

    const float* qb = (dir == 0 ? x : y) + (size_t)(b * PTOT + g * NG) * 3;
    const float* rb = (dir == 0 ? y : x) + (size_t)(b * PTOT + g * NG) * 3;

    // Stage ref slice: 192 floats = 48 float4 (768B slice stride -> 16B aligned).
    if (tid < (SLEN * 3) / 4) {
        float4 v = ((const float4*)(rb + slice * SLEN * 3))[tid];
        ((float4*)raw)[tid] = v;
    }

    // Query loads hoisted above the barrier (8 q x 3 = 6 float4).
    float4 qv[6];
    {
        const float4* qp = (const float4*)(qb + (size_t)tid * QPT * 3);
        #pragma unroll
        for (int i = 0; i < 6; i++) qv[i] = qp[i];
    }

    __syncthreads();

    // Build AoS ref (x,y,z,|r|^2).
    if (tid < SLEN) {
        float rx = raw[tid * 3 + 0];
        float ry = raw[tid * 3 + 1];
        float rz = raw[tid * 3 + 2];
        ref[tid] = make_float4(rx, ry, rz, fmaf(rx, rx, fmaf(ry, ry, rz * rz)));
    }

    // Query-PAIR packed coefficients: axp[p] = {-2x_{2p}, -2x_{2p+1}} etc.
    v2f axp[4], ayp[4], azp[4], qnp[4], mnp[4];
    const float* qf = reinterpret_cast<const float*>(qv);
    #pragma unroll
    for (int p = 0; p < 4; p++) {
        float qx0 = qf[(2*p) * 3 + 0], qx1 = qf[(2*p+1) * 3 + 0];
        float qy0 = qf[(2*p) * 3 + 1], qy1 = qf[(2*p+1) * 3 + 1];
        float qz0 = qf[(2*p) * 3 + 2], qz1 = qf[(2*p+1) * 3 + 2];
        axp[p] = (v2f){-2.0f * qx0, -2.0f * qx1};
        ayp[p] = (v2f){-2.0f * qy0, -2.0f * qy1};
        azp[p] = (v2f){-2.0f * qz0, -2.0f * qz1};
        qnp[p] = (v2f){fmaf(qx0, qx0, fmaf(qy0, qy0, qz0 * qz0)),
                       fmaf(qx1, qx1, fmaf(qy1, qy1, qz1 * qz1))};
        mnp[p] = (v2f){3.4e38f, 3.4e38f};
    }

    __syncthreads();

    // Per 2 refs: 2 broadcast ds_read_b128 + 4 qpairs x (6 pk_fma + 2 min3).
    #pragma unroll 4
    for (int n = 0; n < SLEN; n += 2) {
        float4 r0 = ref[n + 0];
        float4 r1 = ref[n + 1];
        union { float4 f4; v2f h[2]; } u0, u1;
        u0.f4 = r0; u1.f4 = r1;
        v2f r0xy = u0.h[0], r0zw = u0.h[1];
        v2f r1xy = u1.h[0], r1zw = u1.h[1];
        #pragma unroll
        for (int p = 0; p < 4; p++) {
            v2f t0 = pk3(r0xy, r0zw, axp[p], ayp[p], azp[p]);
            v2f t1 = pk3(r1xy, r1zw, axp[p], ayp[p], azp[p]);
            mnp[p].x = fminf(fminf(t0.x, t1.x), mnp[p].x);   // v_min3_f32
            mnp[p].y = fminf(fminf(t0.y, t1.y), mnp[p].y);   // v_min3_f32
        }
    }

    // 8 contiguous floats -> 2x global_store_dwordx4.
    float res[QPT];
    #pragma unroll
    for (int p = 0; p < 4; p++) {
        res[2*p + 0] = mnp[p].x + qnp[p].x;
        res[2*p + 1] = mnp[p].y + qnp[p].y;
    }
    float* op = pmin + (size_t)(prob * S + slice) * NG + tid * QPT;
    #pragma unroll
    for (int i = 0; i < 2; i++)
        ((float4*)op)[i] = make_float4(res[4*i+0], res[4*i+1], res[4*i+2], res[4*i+3]);
}

// Pass 2: per (problem, query) min over the 32 slices, sqrt, block-sum.
__global__ __launch_bounds__(256) void chamfer_pass2(
    const float* __restrict__ pmin, float* __restrict__ bsum)
{
    __shared__ float s4[4];
    const int gid  = blockIdx.x * 256 + threadIdx.x;   // 0..65535
    const int prob = gid >> 11;                        // /2048
    const int q    = gid & (NG - 1);

    float m0 = 3.4e38f, m1 = 3.4e38f;
    #pragma unroll
    for (int s = 0; s < S; s += 2) {
        m0 = fminf(m0, pmin[(size_t)(prob * S + s) * NG + q]);
        m1 = fminf(m1, pmin[(size_t)(prob * S + s + 1) * NG + q]);
    }
    float m = fminf(m0, m1);

    float d = sqrtf(fmaxf(m, 0.0f));   // guard cancellation

    for (int off = 32; off > 0; off >>= 1)
        d += __shfl_down(d, off, 64);
    if ((threadIdx.x & 63) == 0) s4[threadIdx.x >> 6] = d;
    __syncthreads();
    if (threadIdx.x == 0)
        bsum[blockIdx.x] = (s4[0] + s4[1]) + (s4[2] + s4[3]);
}

// Pass 3: deterministic reduction of the 256 block sums.
__global__ __launch_bounds__(256) void chamfer_pass3(
    const float* __restrict__ bsum, float* __restrict__ out)
{
    __shared__ float s4[4];
    const int tid = threadIdx.x;
    float v = bsum[tid];
    for (int off = 32; off > 0; off >>= 1)
        v += __shfl_down(v, off, 64);
    if ((tid & 63) == 0) s4[tid >> 6] = v;
    __syncthreads();
    if (tid == 0)
        out[0] = ((s4[0] + s4[1]) + (s4[2] + s4[3])) * (1.0f / 16384.0f);
}

extern "C" void kernel_launch(void* const* d_in, const int* in_sizes, int n_in,
                              void* d_out, int out_size, void* d_ws, size_t ws_size,
                              hipStream_t stream) {
    const float* x = (const float*)d_in[0];
    const float* y = (const float*)d_in[1];
    float* out  = (float*)d_out;
    float* pmin = (float*)d_ws;                 // 2M floats (8 MB)
    float* bsum = pmin + NPART;                 // 256 floats

    chamfer_pass1<<<NBLK1, NT, 0, stream>>>(x, y, pmin);
    chamfer_pass2<<<256, NT, 0, stream>>>(pmin, bsum);
    chamfer_pass3<<<1, NT, 0, stream>>>(bsum, out);
}